// Round 1
// baseline (1535.049 us; speedup 1.0000x reference)
//
#include <hip/hip_runtime.h>

// ---------------------------------------------------------------------------
// NetGINE: 4x GINEConv (bond-encoder + gather + segment-sum + node MLP + BN)
//          -> concat -> mean-pool per graph -> 4-layer FC head.
// Strategy: CSR-by-dst built per call (no float atomics), wave-per-node
// aggregation (lane = feature), readlane-broadcast matvecs, fp32 throughout.
// ---------------------------------------------------------------------------

__device__ __forceinline__ float rl(float v, int i) {
  return __int_as_float(__builtin_amdgcn_readlane(__float_as_int(v), i));
}

// ---------------- CSR build ----------------

__global__ void hist_kernel(const int* __restrict__ idx, int* __restrict__ cnt, int n) {
  int i = blockIdx.x * blockDim.x + threadIdx.x;
  int stride = gridDim.x * blockDim.x;
  for (; i < n; i += stride) atomicAdd(&cnt[idx[i]], 1);
}

__global__ void fill_kernel(const int* __restrict__ dst, int* __restrict__ cursor,
                            int* __restrict__ sorted, int n) {
  int i = blockIdx.x * blockDim.x + threadIdx.x;
  int stride = gridDim.x * blockDim.x;
  for (; i < n; i += stride) {
    int p = atomicAdd(&cursor[dst[i]], 1);
    sorted[p] = i;
  }
}

// single-block exclusive scan (n up to ~64k); also optionally copies to cursor
__global__ __launch_bounds__(1024) void scan_kernel(const int* __restrict__ cnt,
                                                    int* __restrict__ offs,
                                                    int* __restrict__ cursor, int n) {
  __shared__ int part[1024];
  int tid = threadIdx.x;
  int chunk = (n + 1023) >> 10;
  int s = tid * chunk;
  int e = min(s + chunk, n);
  int sum = 0;
  for (int i = s; i < e; i++) sum += cnt[i];
  part[tid] = sum;
  __syncthreads();
  for (int d = 1; d < 1024; d <<= 1) {
    int v = (tid >= d) ? part[tid - d] : 0;
    __syncthreads();
    part[tid] += v;
    __syncthreads();
  }
  int base = (tid == 0) ? 0 : part[tid - 1];
  for (int i = s; i < e; i++) {
    offs[i] = base;
    if (cursor) cursor[i] = base;
    base += cnt[i];
  }
  if (tid == 1023) offs[n] = part[1023];
}

// ---------------- GIN edge aggregation ----------------
// Per node v: z[v] = (1+eps)*h[v] + sum_{edges (s->v)} relu(h[s] + e_edge)
// where e_edge = relu(attr @ be1) @ be2.
// One wave per node (wave-stride). lane = feature (< DE). be2 column for this
// lane preloaded into DE VGPRs; t (wave-uniform) broadcast via v_readlane.
template <int DE>
__global__ __launch_bounds__(256) void gin_edge_kernel(
    const float* __restrict__ h,       // N x DE
    const float* __restrict__ eattr,   // E x 3
    const float* __restrict__ be1,     // 3 x DE
    const float* __restrict__ be2,     // DE x DE
    const float* __restrict__ epsp,    // [1]
    const int* __restrict__ srcs,      // E
    const int* __restrict__ offs,      // N+1
    const int* __restrict__ sorted,    // E (edge ids grouped by dst)
    float* __restrict__ zout,          // N x DE
    int n_nodes) {
  int wid = (blockIdx.x * blockDim.x + threadIdx.x) >> 6;
  int n_waves = (gridDim.x * blockDim.x) >> 6;
  int lane = threadIdx.x & 63;

  float b10 = 0.f, b11 = 0.f, b12 = 0.f;
  float be2col[DE];
  if (lane < DE) {
    b10 = be1[0 * DE + lane];
    b11 = be1[1 * DE + lane];
    b12 = be1[2 * DE + lane];
#pragma unroll
    for (int i = 0; i < DE; i++) be2col[i] = be2[i * DE + lane];
  } else {
#pragma unroll
    for (int i = 0; i < DE; i++) be2col[i] = 0.f;
  }
  float eps1 = 1.0f + epsp[0];

  for (int v = wid; v < n_nodes; v += n_waves) {
    float acc = (lane < DE) ? eps1 * h[v * DE + lane] : 0.f;
    int e0 = offs[v], e1 = offs[v + 1];
    for (int jj = e0; jj < e1; jj++) {
      int eid = sorted[jj];
      int s = srcs[eid];
      float a0 = eattr[eid * 3 + 0];
      float a1 = eattr[eid * 3 + 1];
      float a2 = eattr[eid * 3 + 2];
      // t (bond-encoder hidden) : lane i holds t_i, wave-uniform content
      float t = fmaxf(fmaf(a0, b10, fmaf(a1, b11, a2 * b12)), 0.f);
      float ev0 = 0.f, ev1 = 0.f;
#pragma unroll
      for (int i = 0; i < DE; i += 2) {
        ev0 = fmaf(rl(t, i), be2col[i], ev0);
        ev1 = fmaf(rl(t, i + 1), be2col[i + 1], ev1);
      }
      float ev = ev0 + ev1;
      float hs = (lane < DE) ? h[s * DE + lane] : 0.f;
      acc += fmaxf(hs + ev, 0.f);
    }
    if (lane < DE) zout[v * DE + lane] = acc;
  }
}

// ---------------- GIN node MLP + outer relu + BN ----------------
// x_out[v] = bn( relu( relu(z @ m1) @ m2 ) )
template <int DIN, int DHID>
__global__ __launch_bounds__(256) void gin_node_kernel(
    const float* __restrict__ z,    // N x DIN
    const float* __restrict__ m1,   // DIN x DHID
    const float* __restrict__ m2,   // DHID x 64
    const float* __restrict__ bng, const float* __restrict__ bnb,
    const float* __restrict__ bnm, const float* __restrict__ bnv,
    float* __restrict__ xout,       // N x 64
    int n_nodes) {
  int wid = (blockIdx.x * blockDim.x + threadIdx.x) >> 6;
  int n_waves = (gridDim.x * blockDim.x) >> 6;
  int lane = threadIdx.x & 63;

  float m1col[DIN];
#pragma unroll
  for (int i = 0; i < DIN; i++) m1col[i] = 0.f;
  if (lane < DHID) {
#pragma unroll
    for (int i = 0; i < DIN; i++) m1col[i] = m1[i * DHID + lane];
  }
  float m2col[DHID];
#pragma unroll
  for (int i = 0; i < DHID; i++) m2col[i] = m2[i * 64 + lane];

  float g = bng[lane], bb = bnb[lane], bm = bnm[lane], bv = bnv[lane];
  float sc = g * rsqrtf(bv + 1e-5f);
  float sh = bb - bm * sc;

  for (int v = wid; v < n_nodes; v += n_waves) {
    float zl = (lane < DIN) ? z[v * DIN + lane] : 0.f;
    float y0 = 0.f, y1 = 0.f;
#pragma unroll
    for (int i = 0; i < DIN; i += 2) {
      y0 = fmaf(rl(zl, i), m1col[i], y0);
      y1 = fmaf(rl(zl, i + 1), m1col[i + 1], y1);
    }
    float y = fmaxf(y0 + y1, 0.f);  // valid for lane < DHID
    float o0 = 0.f, o1 = 0.f;
#pragma unroll
    for (int i = 0; i < DHID; i += 2) {
      o0 = fmaf(rl(y, i), m2col[i], o0);
      o1 = fmaf(rl(y, i + 1), m2col[i + 1], o1);
    }
    float o = fmaxf(o0 + o1, 0.f);          // outer relu
    xout[v * 64 + lane] = fmaf(o, sc, sh);  // BN (eval)
  }
}

// ---------------- graph mean-pool of concat(x1..x4) ----------------
__global__ __launch_bounds__(256) void pool_kernel(
    const float* __restrict__ x1, const float* __restrict__ x2,
    const float* __restrict__ x3, const float* __restrict__ x4,
    const int* __restrict__ goff, float* __restrict__ pooled, int G) {
  int g = blockIdx.x;
  int c = threadIdx.x;            // 0..255
  int sel = c >> 6, f = c & 63;
  const float* x = (sel == 0) ? x1 : (sel == 1) ? x2 : (sel == 2) ? x3 : x4;
  int s = goff[g], e = goff[g + 1];
  float acc = 0.f;
  for (int v = s; v < e; v++) acc += x[v * 64 + f];
  float cnt = (float)(e - s);
  pooled[g * 256 + c] = acc / fmaxf(cnt, 1.0f);
}

// ---------------- FC head ----------------
__global__ __launch_bounds__(64) void head_kernel(
    const float* __restrict__ pooled,
    const float* __restrict__ w1, const float* __restrict__ b1,
    const float* __restrict__ w2, const float* __restrict__ b2,
    const float* __restrict__ w3, const float* __restrict__ b3,
    const float* __restrict__ w4, const float* __restrict__ b4,
    float* __restrict__ out, int G) {
  int g = blockIdx.x;
  int lane = threadIdx.x;  // 64
  __shared__ float sh[256];
  for (int i = lane; i < 256; i += 64) sh[i] = pooled[g * 256 + i];
  __syncthreads();
  float h1 = b1[lane];
#pragma unroll 8
  for (int i = 0; i < 256; i++) h1 = fmaf(sh[i], w1[i * 64 + lane], h1);
  h1 = fmaxf(h1, 0.f);
  __syncthreads();
  sh[lane] = h1;
  __syncthreads();
  float h2 = b2[lane];
#pragma unroll
  for (int i = 0; i < 64; i++) h2 = fmaf(sh[i], w2[i * 64 + lane], h2);
  h2 = fmaxf(h2, 0.f);
  __syncthreads();
  sh[lane] = h2;
  __syncthreads();
  float h3 = b3[lane];
#pragma unroll
  for (int i = 0; i < 64; i++) h3 = fmaf(sh[i], w3[i * 64 + lane], h3);
  h3 = fmaxf(h3, 0.f);
  float p = h3 * w4[lane];  // fc4_w is (64,1)
  for (int d = 32; d > 0; d >>= 1) p += __shfl_down(p, d);
  if (lane == 0) out[g] = p + b4[0];
}

// ---------------------------------------------------------------------------

extern "C" void kernel_launch(void* const* d_in, const int* in_sizes, int n_in,
                              void* d_out, int out_size, void* d_ws, size_t ws_size,
                              hipStream_t stream) {
  const float* x      = (const float*)d_in[0];
  const float* eattr  = (const float*)d_in[1];
  const float* c1_be1 = (const float*)d_in[2];
  const float* c1_be2 = (const float*)d_in[3];
  const float* c1_m1  = (const float*)d_in[4];
  const float* c1_m2  = (const float*)d_in[5];
  const float* c1_eps = (const float*)d_in[6];
  const float* c2_be1 = (const float*)d_in[7];
  const float* c2_be2 = (const float*)d_in[8];
  const float* c2_m1  = (const float*)d_in[9];
  const float* c2_m2  = (const float*)d_in[10];
  const float* c2_eps = (const float*)d_in[11];
  const float* c3_be1 = (const float*)d_in[12];
  const float* c3_be2 = (const float*)d_in[13];
  const float* c3_m1  = (const float*)d_in[14];
  const float* c3_m2  = (const float*)d_in[15];
  const float* c3_eps = (const float*)d_in[16];
  const float* bn_g[4] = {(const float*)d_in[17], (const float*)d_in[21],
                          (const float*)d_in[25], (const float*)d_in[29]};
  const float* bn_b[4] = {(const float*)d_in[18], (const float*)d_in[22],
                          (const float*)d_in[26], (const float*)d_in[30]};
  const float* bn_m[4] = {(const float*)d_in[19], (const float*)d_in[23],
                          (const float*)d_in[27], (const float*)d_in[31]};
  const float* bn_v[4] = {(const float*)d_in[20], (const float*)d_in[24],
                          (const float*)d_in[28], (const float*)d_in[32]};
  const float* fc1_w = (const float*)d_in[33];
  const float* fc1_b = (const float*)d_in[34];
  const float* fc2_w = (const float*)d_in[35];
  const float* fc2_b = (const float*)d_in[36];
  const float* fc3_w = (const float*)d_in[37];
  const float* fc3_b = (const float*)d_in[38];
  const float* fc4_w = (const float*)d_in[39];
  const float* fc4_b = (const float*)d_in[40];
  const int* eidx  = (const int*)d_in[41];
  const int* batch = (const int*)d_in[42];

  const int N = in_sizes[0] / 28;
  const int E = in_sizes[1] / 3;
  const int G = out_size;
  const int* src = eidx;
  const int* dst = eidx + E;
  float* outf = (float*)d_out;

  // workspace carve-out (all 256B aligned)
  char* p = (char*)d_ws;
  auto alloc = [&](size_t bytes) {
    char* r = p;
    p += (bytes + 255) & ~(size_t)255;
    return r;
  };
  int* counts   = (int*)alloc((size_t)N * 4);
  int* offs     = (int*)alloc((size_t)(N + 1) * 4);
  int* cursor   = (int*)alloc((size_t)N * 4);
  int* sorted   = (int*)alloc((size_t)E * 4);
  int* gcnt     = (int*)alloc((size_t)G * 4);
  int* goff     = (int*)alloc((size_t)(G + 1) * 4);
  float* zbuf   = (float*)alloc((size_t)N * 64 * 4);
  float* x1     = (float*)alloc((size_t)N * 64 * 4);
  float* x2     = (float*)alloc((size_t)N * 64 * 4);
  float* x3     = (float*)alloc((size_t)N * 64 * 4);
  float* x4     = (float*)alloc((size_t)N * 64 * 4);
  float* pooled = (float*)alloc((size_t)G * 256 * 4);
  (void)ws_size; (void)n_in;

  hipMemsetAsync(counts, 0, (size_t)N * 4, stream);
  hipMemsetAsync(gcnt, 0, (size_t)G * 4, stream);
  hist_kernel<<<1024, 256, 0, stream>>>(dst, counts, E);
  hist_kernel<<<256, 256, 0, stream>>>(batch, gcnt, N);
  scan_kernel<<<1, 1024, 0, stream>>>(counts, offs, cursor, N);
  scan_kernel<<<1, 1024, 0, stream>>>(gcnt, goff, nullptr, G);
  fill_kernel<<<1024, 256, 0, stream>>>(dst, cursor, sorted, E);

  dim3 blk(256), grd(1024);
  // layer 1 (28-dim edge part)
  gin_edge_kernel<28><<<grd, blk, 0, stream>>>(x, eattr, c1_be1, c1_be2, c1_eps,
                                               src, offs, sorted, zbuf, N);
  gin_node_kernel<28, 28><<<grd, blk, 0, stream>>>(zbuf, c1_m1, c1_m2, bn_g[0],
                                                   bn_b[0], bn_m[0], bn_v[0], x1, N);
  // layer 2
  gin_edge_kernel<64><<<grd, blk, 0, stream>>>(x1, eattr, c2_be1, c2_be2, c2_eps,
                                               src, offs, sorted, zbuf, N);
  gin_node_kernel<64, 64><<<grd, blk, 0, stream>>>(zbuf, c2_m1, c2_m2, bn_g[1],
                                                   bn_b[1], bn_m[1], bn_v[1], x2, N);
  // layer 3
  gin_edge_kernel<64><<<grd, blk, 0, stream>>>(x2, eattr, c3_be1, c3_be2, c3_eps,
                                               src, offs, sorted, zbuf, N);
  gin_node_kernel<64, 64><<<grd, blk, 0, stream>>>(zbuf, c3_m1, c3_m2, bn_g[2],
                                                   bn_b[2], bn_m[2], bn_v[2], x3, N);
  // layer 4 (conv3 weights reused)
  gin_edge_kernel<64><<<grd, blk, 0, stream>>>(x3, eattr, c3_be1, c3_be2, c3_eps,
                                               src, offs, sorted, zbuf, N);
  gin_node_kernel<64, 64><<<grd, blk, 0, stream>>>(zbuf, c3_m1, c3_m2, bn_g[3],
                                                   bn_b[3], bn_m[3], bn_v[3], x4, N);

  pool_kernel<<<G, 256, 0, stream>>>(x1, x2, x3, x4, goff, pooled, G);
  head_kernel<<<G, 64, 0, stream>>>(pooled, fc1_w, fc1_b, fc2_w, fc2_b, fc3_w,
                                    fc3_b, fc4_w, fc4_b, outf, G);
}

// Round 3
// 881.674 us; speedup vs baseline: 1.7411x; 1.7411x over previous
//
#include <hip/hip_runtime.h>

// ---------------------------------------------------------------------------
// NetGINE restructured:
//   CSR build (by dst) + permuted edge tables
//   bond_kernel: ebond = relu(attr@be1)@be2 via bf16 MFMA, stored bf16 in
//                dst-sorted order (3 unique weight sets; layer4 reuses layer3)
//   agg_kernel:  z[v] = (1+eps)h[v] + sum relu(h[src] + ebond)   (light, ILP)
//   node_mfma_kernel: x = bn(relu(relu(z@m1)@m2)) via 2 chained MFMA GEMMs
//   pool + FC head (unchanged from passing round 1)
// ---------------------------------------------------------------------------

typedef __attribute__((ext_vector_type(8))) short short8v;
typedef __attribute__((ext_vector_type(4))) float float4v;

__device__ __forceinline__ unsigned short f2bf(float f) {  // RNE f32->bf16
  unsigned u = __float_as_uint(f);
  u += 0x7fff + ((u >> 16) & 1);
  return (unsigned short)(u >> 16);
}
__device__ __forceinline__ float bf2f(unsigned short s) {
  return __uint_as_float(((unsigned)s) << 16);
}
__device__ __forceinline__ float4v mfma16(short8v a, short8v b, float4v c) {
  return __builtin_amdgcn_mfma_f32_16x16x32_bf16(a, b, c, 0, 0, 0);
}

// ---------------- CSR build ----------------

__global__ void hist_kernel(const int* __restrict__ idx, int* __restrict__ cnt, int n) {
  int i = blockIdx.x * blockDim.x + threadIdx.x;
  int stride = gridDim.x * blockDim.x;
  for (; i < n; i += stride) atomicAdd(&cnt[idx[i]], 1);
}

__global__ void fill_kernel(const int* __restrict__ dst, int* __restrict__ cursor,
                            int* __restrict__ sorted, int n) {
  int i = blockIdx.x * blockDim.x + threadIdx.x;
  int stride = gridDim.x * blockDim.x;
  for (; i < n; i += stride) {
    int p = atomicAdd(&cursor[dst[i]], 1);
    sorted[p] = i;
  }
}

__global__ __launch_bounds__(1024) void scan_kernel(const int* __restrict__ cnt,
                                                    int* __restrict__ offs,
                                                    int* __restrict__ cursor, int n) {
  __shared__ int part[1024];
  int tid = threadIdx.x;
  int chunk = (n + 1023) >> 10;
  int s = tid * chunk;
  int e = min(s + chunk, n);
  int sum = 0;
  for (int i = s; i < e; i++) sum += cnt[i];
  part[tid] = sum;
  __syncthreads();
  for (int d = 1; d < 1024; d <<= 1) {
    int v = (tid >= d) ? part[tid - d] : 0;
    __syncthreads();
    part[tid] += v;
    __syncthreads();
  }
  int base = (tid == 0) ? 0 : part[tid - 1];
  for (int i = s; i < e; i++) {
    offs[i] = base;
    if (cursor) cursor[i] = base;
    base += cnt[i];
  }
  if (tid == 1023) offs[n] = part[1023];
}

// permute edge tables into dst-sorted order
__global__ void perm_kernel(const int* __restrict__ sorted, const int* __restrict__ srcs,
                            const float* __restrict__ eattr, int* __restrict__ src_sorted,
                            float4* __restrict__ attr_s, int E) {
  int i = blockIdx.x * blockDim.x + threadIdx.x;
  int stride = gridDim.x * blockDim.x;
  for (; i < E; i += stride) {
    int eid = sorted[i];
    src_sorted[i] = srcs[eid];
    attr_s[i] = make_float4(eattr[eid * 3 + 0], eattr[eid * 3 + 1], eattr[eid * 3 + 2], 0.f);
  }
}

// ---------------- bond encoder GEMM (MFMA) ----------------
// ebond[j][f] = ( relu(attr_s[j] @ be1) @ be2 )[f]  as bf16, j in sorted order.
// Per wave: 16-edge tiles. t computed lane=feature, transposed through LDS,
// A-frag layout: lane l holds A[row=l&15][k=(l>>4)*8+j]; B preloaded frags.
template <int DE>
__global__ __launch_bounds__(256) void bond_kernel(
    const float4* __restrict__ attr_s, const float* __restrict__ be1,
    const float* __restrict__ be2, unsigned short* __restrict__ ebond, int E) {
  constexpr int KT = (DE + 31) / 32;   // 1 (DE=28) or 2 (DE=64)
  constexpr int NT = (DE + 15) / 16;   // 2 or 4
  constexpr int RB = KT * 32;          // ebond row width: 32 or 64
  constexpr int LROW = RB * 2 + 16;    // padded LDS row bytes (80 / 144), 16B-aligned
  __shared__ __attribute__((aligned(16))) char lds_all[4 * 16 * LROW];
  char* lds = lds_all + (threadIdx.x >> 6) * (16 * LROW);
  int lane = threadIdx.x & 63;
  int nc = lane & 15, kr = (lane >> 4) * 8, rr = (lane >> 4) * 4;
  int gw = (blockIdx.x * blockDim.x + threadIdx.x) >> 6;
  int nw = (gridDim.x * blockDim.x) >> 6;

  float b10 = 0.f, b11 = 0.f, b12 = 0.f;
  if (lane < DE) { b10 = be1[lane]; b11 = be1[DE + lane]; b12 = be1[2 * DE + lane]; }

  short8v bfrag[NT][KT];
#pragma unroll
  for (int nt = 0; nt < NT; nt++)
#pragma unroll
    for (int kt = 0; kt < KT; kt++) {
      short8v f;
#pragma unroll
      for (int j = 0; j < 8; j++) {
        int k = kt * 32 + kr + j, n = nt * 16 + nc;
        float w = (k < DE && n < DE) ? be2[k * DE + n] : 0.f;
        f[j] = (short)f2bf(w);
      }
      bfrag[nt][kt] = f;
    }

  int ntiles = (E + 15) >> 4;
  for (int tile = gw; tile < ntiles; tile += nw) {
    int j0 = __builtin_amdgcn_readfirstlane(tile) << 4;
#pragma unroll
    for (int e = 0; e < 16; e++) {
      int j = j0 + e;
      float t = 0.f;
      if (j < E) {
        float4 a = attr_s[j];  // wave-uniform -> s_load
        t = fmaxf(fmaf(a.x, b10, fmaf(a.y, b11, a.z * b12)), 0.f);
      }
      *(unsigned short*)(lds + e * LROW + lane * 2) = f2bf(t);
    }
    asm volatile("" ::: "memory");  // order LDS writes before reads (same wave)
    short8v af[KT];
#pragma unroll
    for (int kt = 0; kt < KT; kt++)
      af[kt] = *(const short8v*)(lds + (lane & 15) * LROW + (lane >> 4) * 16 + kt * 64);
    float4v acc[NT];
#pragma unroll
    for (int nt = 0; nt < NT; nt++) {
      acc[nt] = (float4v){0.f, 0.f, 0.f, 0.f};
#pragma unroll
      for (int kt = 0; kt < KT; kt++) acc[nt] = mfma16(af[kt], bfrag[nt][kt], acc[nt]);
    }
#pragma unroll
    for (int nt = 0; nt < NT; nt++)
#pragma unroll
      for (int r = 0; r < 4; r++) {
        int row = j0 + rr + r;
        if (row < E) ebond[(size_t)row * RB + nt * 16 + nc] = f2bf(acc[nt][r]);
      }
    asm volatile("" ::: "memory");  // don't let next tile's writes cross this tile's reads
  }
}

// ---------------- edge aggregation (light) ----------------
// z[v] = (1+eps)*h[v] + sum_j relu(h[src_sorted[j]] + bf2f(ebond[j]))
// DH: h row width (28 or 64). RB: ebond/z row width (32 or 64).
template <int DH, int RB>
__global__ __launch_bounds__(256) void agg_kernel(
    const float* __restrict__ h, const unsigned short* __restrict__ eb,
    const float* __restrict__ epsp, const int* __restrict__ src_sorted,
    const int* __restrict__ offs, float* __restrict__ zout, int n_nodes) {
  int wid = (blockIdx.x * blockDim.x + threadIdx.x) >> 6;
  int nw = (gridDim.x * blockDim.x) >> 6;
  int lane = threadIdx.x & 63;
  float eps1 = 1.f + epsp[0];
  const bool hl = (DH == 64) || (lane < DH);
  const bool el = (RB == 64) || (lane < RB);
  for (int v = wid; v < n_nodes; v += nw) {
    float acc = hl ? eps1 * h[(size_t)v * DH + lane] : 0.f;
    int j = offs[v], e1 = offs[v + 1];
    for (; j + 3 < e1; j += 4) {
      int s0 = src_sorted[j], s1 = src_sorted[j + 1];
      int s2 = src_sorted[j + 2], s3 = src_sorted[j + 3];
      float b0 = el ? bf2f(eb[(size_t)j * RB + lane]) : 0.f;
      float b1 = el ? bf2f(eb[(size_t)(j + 1) * RB + lane]) : 0.f;
      float b2 = el ? bf2f(eb[(size_t)(j + 2) * RB + lane]) : 0.f;
      float b3 = el ? bf2f(eb[(size_t)(j + 3) * RB + lane]) : 0.f;
      float h0 = hl ? h[(size_t)s0 * DH + lane] : 0.f;
      float h1 = hl ? h[(size_t)s1 * DH + lane] : 0.f;
      float h2 = hl ? h[(size_t)s2 * DH + lane] : 0.f;
      float h3 = hl ? h[(size_t)s3 * DH + lane] : 0.f;
      acc += fmaxf(h0 + b0, 0.f) + fmaxf(h1 + b1, 0.f) +
             fmaxf(h2 + b2, 0.f) + fmaxf(h3 + b3, 0.f);
    }
    for (; j < e1; j++) {
      int s = src_sorted[j];
      float b = el ? bf2f(eb[(size_t)j * RB + lane]) : 0.f;
      float hs = hl ? h[(size_t)s * DH + lane] : 0.f;
      acc += fmaxf(hs + b, 0.f);
    }
    if (el) zout[(size_t)v * RB + lane] = acc;
  }
}

// ---------------- node MLP + relu + BN (MFMA) ----------------
// x[v] = bn( relu( relu(z@m1) @ m2 ) ).  z rows are ZR=KT*32 wide (zero-padded).
template <int DIN>
__global__ __launch_bounds__(256) void node_mfma_kernel(
    const float* __restrict__ z, const float* __restrict__ m1,
    const float* __restrict__ m2, const float* __restrict__ bng,
    const float* __restrict__ bnb, const float* __restrict__ bnm,
    const float* __restrict__ bnv, float* __restrict__ xout, int n_nodes) {
  constexpr int KT = (DIN + 31) / 32;   // 1 or 2
  constexpr int NTH = (DIN + 15) / 16;  // hidden N-tiles: 2 or 4
  constexpr int ZR = KT * 32;
  constexpr int LROW = ZR * 2 + 16;
  __shared__ __attribute__((aligned(16))) char lds_all[8 * 16 * LROW];
  char* zl = lds_all + (threadIdx.x >> 6) * (16 * LROW);
  char* yl = lds_all + (4 + (threadIdx.x >> 6)) * (16 * LROW);
  int lane = threadIdx.x & 63;
  int nc = lane & 15, kr = (lane >> 4) * 8, rr = (lane >> 4) * 4;
  int gw = (blockIdx.x * blockDim.x + threadIdx.x) >> 6;
  int nw = (gridDim.x * blockDim.x) >> 6;

  short8v m1f[NTH][KT], m2f[4][KT];
#pragma unroll
  for (int nt = 0; nt < NTH; nt++)
#pragma unroll
    for (int kt = 0; kt < KT; kt++) {
      short8v f;
#pragma unroll
      for (int j = 0; j < 8; j++) {
        int k = kt * 32 + kr + j, n = nt * 16 + nc;
        float w = (k < DIN && n < DIN) ? m1[k * DIN + n] : 0.f;
        f[j] = (short)f2bf(w);
      }
      m1f[nt][kt] = f;
    }
#pragma unroll
  for (int nt = 0; nt < 4; nt++)
#pragma unroll
    for (int kt = 0; kt < KT; kt++) {
      short8v f;
#pragma unroll
      for (int j = 0; j < 8; j++) {
        int k = kt * 32 + kr + j, n = nt * 16 + nc;
        float w = (k < DIN) ? m2[k * 64 + n] : 0.f;
        f[j] = (short)f2bf(w);
      }
      m2f[nt][kt] = f;
    }
  float scv[4], shv[4];
#pragma unroll
  for (int nt = 0; nt < 4; nt++) {
    int f = nt * 16 + nc;
    float sc = bng[f] * rsqrtf(bnv[f] + 1e-5f);
    scv[nt] = sc;
    shv[nt] = bnb[f] - bnm[f] * sc;
  }

  int ntiles = (n_nodes + 15) >> 4;
  for (int tile = gw; tile < ntiles; tile += nw) {
    int v0 = __builtin_amdgcn_readfirstlane(tile) << 4;
#pragma unroll
    for (int r = 0; r < 16; r++) {
      int v = v0 + r;
      float zv = (v < n_nodes && lane < ZR) ? z[(size_t)v * ZR + lane] : 0.f;
      if (lane < ZR) *(unsigned short*)(zl + r * LROW + lane * 2) = f2bf(zv);
    }
    asm volatile("" ::: "memory");
    short8v af[KT];
#pragma unroll
    for (int kt = 0; kt < KT; kt++)
      af[kt] = *(const short8v*)(zl + (lane & 15) * LROW + (lane >> 4) * 16 + kt * 64);
    float4v acch[NTH];
#pragma unroll
    for (int nt = 0; nt < NTH; nt++) {
      acch[nt] = (float4v){0.f, 0.f, 0.f, 0.f};
#pragma unroll
      for (int kt = 0; kt < KT; kt++) acch[nt] = mfma16(af[kt], m1f[nt][kt], acch[nt]);
    }
    // hidden y = relu(.) back to LDS (bf16) in row-major for 2nd A-frag read
#pragma unroll
    for (int nt = 0; nt < NTH; nt++)
#pragma unroll
      for (int r = 0; r < 4; r++)
        *(unsigned short*)(yl + (rr + r) * LROW + (nt * 16 + nc) * 2) =
            f2bf(fmaxf(acch[nt][r], 0.f));
    asm volatile("" ::: "memory");
    short8v af2[KT];
#pragma unroll
    for (int kt = 0; kt < KT; kt++)
      af2[kt] = *(const short8v*)(yl + (lane & 15) * LROW + (lane >> 4) * 16 + kt * 64);
    float4v acco[4];
#pragma unroll
    for (int nt = 0; nt < 4; nt++) {
      acco[nt] = (float4v){0.f, 0.f, 0.f, 0.f};
#pragma unroll
      for (int kt = 0; kt < KT; kt++) acco[nt] = mfma16(af2[kt], m2f[nt][kt], acco[nt]);
    }
#pragma unroll
    for (int nt = 0; nt < 4; nt++)
#pragma unroll
      for (int r = 0; r < 4; r++) {
        int v = v0 + rr + r;
        if (v < n_nodes)
          xout[(size_t)v * 64 + nt * 16 + nc] =
              fmaf(fmaxf(acco[nt][r], 0.f), scv[nt], shv[nt]);
      }
    asm volatile("" ::: "memory");
  }
}

// ---------------- graph mean-pool of concat(x1..x4) ----------------
__global__ __launch_bounds__(256) void pool_kernel(
    const float* __restrict__ x1, const float* __restrict__ x2,
    const float* __restrict__ x3, const float* __restrict__ x4,
    const int* __restrict__ goff, float* __restrict__ pooled, int G) {
  int g = blockIdx.x;
  int c = threadIdx.x;
  int sel = c >> 6, f = c & 63;
  const float* x = (sel == 0) ? x1 : (sel == 1) ? x2 : (sel == 2) ? x3 : x4;
  int s = goff[g], e = goff[g + 1];
  float acc = 0.f;
  for (int v = s; v < e; v++) acc += x[(size_t)v * 64 + f];
  float cnt = (float)(e - s);
  pooled[g * 256 + c] = acc / fmaxf(cnt, 1.0f);
}

// ---------------- FC head ----------------
__global__ __launch_bounds__(64) void head_kernel(
    const float* __restrict__ pooled,
    const float* __restrict__ w1, const float* __restrict__ b1,
    const float* __restrict__ w2, const float* __restrict__ b2,
    const float* __restrict__ w3, const float* __restrict__ b3,
    const float* __restrict__ w4, const float* __restrict__ b4,
    float* __restrict__ out, int G) {
  int g = blockIdx.x;
  int lane = threadIdx.x;
  __shared__ float sh[256];
  for (int i = lane; i < 256; i += 64) sh[i] = pooled[g * 256 + i];
  __syncthreads();
  float h1 = b1[lane];
#pragma unroll 8
  for (int i = 0; i < 256; i++) h1 = fmaf(sh[i], w1[i * 64 + lane], h1);
  h1 = fmaxf(h1, 0.f);
  __syncthreads();
  sh[lane] = h1;
  __syncthreads();
  float h2 = b2[lane];
#pragma unroll
  for (int i = 0; i < 64; i++) h2 = fmaf(sh[i], w2[i * 64 + lane], h2);
  h2 = fmaxf(h2, 0.f);
  __syncthreads();
  sh[lane] = h2;
  __syncthreads();
  float h3 = b3[lane];
#pragma unroll
  for (int i = 0; i < 64; i++) h3 = fmaf(sh[i], w3[i * 64 + lane], h3);
  h3 = fmaxf(h3, 0.f);
  float p = h3 * w4[lane];
  for (int d = 32; d > 0; d >>= 1) p += __shfl_down(p, d);
  if (lane == 0) out[g] = p + b4[0];
}

// ---------------------------------------------------------------------------

extern "C" void kernel_launch(void* const* d_in, const int* in_sizes, int n_in,
                              void* d_out, int out_size, void* d_ws, size_t ws_size,
                              hipStream_t stream) {
  const float* x      = (const float*)d_in[0];
  const float* eattr  = (const float*)d_in[1];
  const float* c1_be1 = (const float*)d_in[2];
  const float* c1_be2 = (const float*)d_in[3];
  const float* c1_m1  = (const float*)d_in[4];
  const float* c1_m2  = (const float*)d_in[5];
  const float* c1_eps = (const float*)d_in[6];
  const float* c2_be1 = (const float*)d_in[7];
  const float* c2_be2 = (const float*)d_in[8];
  const float* c2_m1  = (const float*)d_in[9];
  const float* c2_m2  = (const float*)d_in[10];
  const float* c2_eps = (const float*)d_in[11];
  const float* c3_be1 = (const float*)d_in[12];
  const float* c3_be2 = (const float*)d_in[13];
  const float* c3_m1  = (const float*)d_in[14];
  const float* c3_m2  = (const float*)d_in[15];
  const float* c3_eps = (const float*)d_in[16];
  const float* bn_g[4] = {(const float*)d_in[17], (const float*)d_in[21],
                          (const float*)d_in[25], (const float*)d_in[29]};
  const float* bn_b[4] = {(const float*)d_in[18], (const float*)d_in[22],
                          (const float*)d_in[26], (const float*)d_in[30]};
  const float* bn_m[4] = {(const float*)d_in[19], (const float*)d_in[23],
                          (const float*)d_in[27], (const float*)d_in[31]};
  const float* bn_v[4] = {(const float*)d_in[20], (const float*)d_in[24],
                          (const float*)d_in[28], (const float*)d_in[32]};
  const float* fc1_w = (const float*)d_in[33];
  const float* fc1_b = (const float*)d_in[34];
  const float* fc2_w = (const float*)d_in[35];
  const float* fc2_b = (const float*)d_in[36];
  const float* fc3_w = (const float*)d_in[37];
  const float* fc3_b = (const float*)d_in[38];
  const float* fc4_w = (const float*)d_in[39];
  const float* fc4_b = (const float*)d_in[40];
  const int* eidx  = (const int*)d_in[41];
  const int* batch = (const int*)d_in[42];

  const int N = in_sizes[0] / 28;
  const int E = in_sizes[1] / 3;
  const int G = out_size;
  const int* src = eidx;
  const int* dst = eidx + E;
  float* outf = (float*)d_out;

  char* p = (char*)d_ws;
  auto alloc = [&](size_t bytes) {
    char* r = p;
    p += (bytes + 255) & ~(size_t)255;
    return r;
  };
  int* counts   = (int*)alloc((size_t)N * 4);
  int* offs     = (int*)alloc((size_t)(N + 1) * 4);
  int* cursor   = (int*)alloc((size_t)N * 4);
  int* sorted   = (int*)alloc((size_t)E * 4);
  int* gcnt     = (int*)alloc((size_t)G * 4);
  int* goff     = (int*)alloc((size_t)(G + 1) * 4);
  int* src_s    = (int*)alloc((size_t)E * 4);
  float4* attr_s = (float4*)alloc((size_t)E * 16);
  unsigned short* ebond = (unsigned short*)alloc((size_t)E * 64 * 2);  // reused per layer
  float* zbuf   = (float*)alloc((size_t)N * 64 * 4);
  float* x1     = (float*)alloc((size_t)N * 64 * 4);
  float* x2     = (float*)alloc((size_t)N * 64 * 4);
  float* x3     = (float*)alloc((size_t)N * 64 * 4);
  float* x4     = (float*)alloc((size_t)N * 64 * 4);
  float* pooled = (float*)alloc((size_t)G * 256 * 4);
  (void)ws_size; (void)n_in;

  hipMemsetAsync(counts, 0, (size_t)N * 4, stream);
  hipMemsetAsync(gcnt, 0, (size_t)G * 4, stream);
  hist_kernel<<<1024, 256, 0, stream>>>(dst, counts, E);
  hist_kernel<<<256, 256, 0, stream>>>(batch, gcnt, N);
  scan_kernel<<<1, 1024, 0, stream>>>(counts, offs, cursor, N);
  scan_kernel<<<1, 1024, 0, stream>>>(gcnt, goff, nullptr, G);
  fill_kernel<<<1024, 256, 0, stream>>>(dst, cursor, sorted, E);
  perm_kernel<<<1024, 256, 0, stream>>>(sorted, src, eattr, src_s, attr_s, E);

  dim3 blk(256);
  // layer 1
  bond_kernel<28><<<1024, blk, 0, stream>>>(attr_s, c1_be1, c1_be2, ebond, E);
  agg_kernel<28, 32><<<2048, blk, 0, stream>>>(x, ebond, c1_eps, src_s, offs, zbuf, N);
  node_mfma_kernel<28><<<1024, blk, 0, stream>>>(zbuf, c1_m1, c1_m2, bn_g[0], bn_b[0],
                                                 bn_m[0], bn_v[0], x1, N);
  // layer 2
  bond_kernel<64><<<1024, blk, 0, stream>>>(attr_s, c2_be1, c2_be2, ebond, E);
  agg_kernel<64, 64><<<2048, blk, 0, stream>>>(x1, ebond, c2_eps, src_s, offs, zbuf, N);
  node_mfma_kernel<64><<<1024, blk, 0, stream>>>(zbuf, c2_m1, c2_m2, bn_g[1], bn_b[1],
                                                 bn_m[1], bn_v[1], x2, N);
  // layer 3
  bond_kernel<64><<<1024, blk, 0, stream>>>(attr_s, c3_be1, c3_be2, ebond, E);
  agg_kernel<64, 64><<<2048, blk, 0, stream>>>(x2, ebond, c3_eps, src_s, offs, zbuf, N);
  node_mfma_kernel<64><<<1024, blk, 0, stream>>>(zbuf, c3_m1, c3_m2, bn_g[2], bn_b[2],
                                                 bn_m[2], bn_v[2], x3, N);
  // layer 4 (conv3 weights reused -> ebond already holds c3 bond encodings)
  agg_kernel<64, 64><<<2048, blk, 0, stream>>>(x3, ebond, c3_eps, src_s, offs, zbuf, N);
  node_mfma_kernel<64><<<1024, blk, 0, stream>>>(zbuf, c3_m1, c3_m2, bn_g[3], bn_b[3],
                                                 bn_m[3], bn_v[3], x4, N);

  pool_kernel<<<G, blk, 0, stream>>>(x1, x2, x3, x4, goff, pooled, G);
  head_kernel<<<G, 64, 0, stream>>>(pooled, fc1_w, fc1_b, fc2_w, fc2_b, fc3_w,
                                    fc3_b, fc4_w, fc4_b, outf, G);
}

// Round 4
// 765.125 us; speedup vs baseline: 2.0063x; 1.1523x over previous
//
#include <hip/hip_runtime.h>

// ---------------------------------------------------------------------------
// NetGINE:
//   CSR build (by dst): hist + 3-kernel hierarchical scan + fill + perm
//   goff: binary search over sorted batch (no hist/scan)
//   bond_kernel: ebond = relu(attr@be1)@be2 via bf16 MFMA (dst-sorted bf16)
//   agg_kernel:  z[v] = (1+eps)h[v] + sum relu(h[src] + ebond)
//   node_mfma_kernel: x = bn(relu(relu(z@m1)@m2)) via 2 chained MFMA GEMMs
//   pool + FC head
// ---------------------------------------------------------------------------

typedef __attribute__((ext_vector_type(8))) short short8v;
typedef __attribute__((ext_vector_type(4))) float float4v;

__device__ __forceinline__ unsigned short f2bf(float f) {  // RNE f32->bf16
  unsigned u = __float_as_uint(f);
  u += 0x7fff + ((u >> 16) & 1);
  return (unsigned short)(u >> 16);
}
__device__ __forceinline__ float bf2f(unsigned short s) {
  return __uint_as_float(((unsigned)s) << 16);
}
__device__ __forceinline__ float4v mfma16(short8v a, short8v b, float4v c) {
  return __builtin_amdgcn_mfma_f32_16x16x32_bf16(a, b, c, 0, 0, 0);
}

// ---------------- CSR build ----------------

__global__ void hist_kernel(const int* __restrict__ idx, int* __restrict__ cnt, int n) {
  int i = blockIdx.x * blockDim.x + threadIdx.x;
  int stride = gridDim.x * blockDim.x;
  for (; i < n; i += stride) atomicAdd(&cnt[idx[i]], 1);
}

__global__ void fill_kernel(const int* __restrict__ dst, int* __restrict__ cursor,
                            int* __restrict__ sorted, int n) {
  int i = blockIdx.x * blockDim.x + threadIdx.x;
  int stride = gridDim.x * blockDim.x;
  for (; i < n; i += stride) {
    int p = atomicAdd(&cursor[dst[i]], 1);
    sorted[p] = i;
  }
}

// --- hierarchical exclusive scan of counts[n] -> offs[n+1], cursor copy ---
__global__ __launch_bounds__(256) void block_reduce_kernel(
    const int* __restrict__ cnt, int* __restrict__ bsum, int n) {
  __shared__ int s[256];
  int i = blockIdx.x * 256 + threadIdx.x;
  s[threadIdx.x] = (i < n) ? cnt[i] : 0;
  __syncthreads();
  for (int d = 128; d > 0; d >>= 1) {
    if (threadIdx.x < d) s[threadIdx.x] += s[threadIdx.x + d];
    __syncthreads();
  }
  if (threadIdx.x == 0) bsum[blockIdx.x] = s[0];
}

__global__ __launch_bounds__(256) void bsum_scan_kernel(int* __restrict__ bsum, int nb) {
  __shared__ int s[1024];
  for (int i = threadIdx.x; i < 1024; i += 256) s[i] = (i < nb) ? bsum[i] : 0;
  __syncthreads();
  if (threadIdx.x == 0) {  // nb <= ~1024, serial scan is ~1us
    int acc = 0;
    for (int i = 0; i < nb; i++) { int t = s[i]; s[i] = acc; acc += t; }
  }
  __syncthreads();
  for (int i = threadIdx.x; i < nb; i += 256) bsum[i] = s[i];
}

__global__ __launch_bounds__(256) void scan_apply_kernel(
    const int* __restrict__ cnt, const int* __restrict__ bsum,
    int* __restrict__ offs, int* __restrict__ cursor, int n) {
  __shared__ int s[256];
  int b = blockIdx.x;
  int i = b * 256 + threadIdx.x;
  int v = (i < n) ? cnt[i] : 0;
  s[threadIdx.x] = v;
  __syncthreads();
  for (int d = 1; d < 256; d <<= 1) {
    int t = (threadIdx.x >= d) ? s[threadIdx.x - d] : 0;
    __syncthreads();
    s[threadIdx.x] += t;
    __syncthreads();
  }
  int excl = s[threadIdx.x] - v + bsum[b];
  if (i < n) { offs[i] = excl; cursor[i] = excl; }
  if (i == n - 1) offs[n] = excl + v;
}

// --- graph boundaries from sorted batch: goff[g] = lower_bound(batch, g) ---
__global__ void boundary_kernel(const int* __restrict__ batch, int* __restrict__ goff,
                                int n, int G) {
  int g = blockIdx.x * blockDim.x + threadIdx.x;
  if (g > G) return;
  int lo = 0, hi = n;
  while (lo < hi) {
    int mid = (lo + hi) >> 1;
    if (batch[mid] < g) lo = mid + 1; else hi = mid;
  }
  goff[g] = lo;
}

// permute edge tables into dst-sorted order
__global__ void perm_kernel(const int* __restrict__ sorted, const int* __restrict__ srcs,
                            const float* __restrict__ eattr, int* __restrict__ src_sorted,
                            float4* __restrict__ attr_s, int E) {
  int i = blockIdx.x * blockDim.x + threadIdx.x;
  int stride = gridDim.x * blockDim.x;
  for (; i < E; i += stride) {
    int eid = sorted[i];
    src_sorted[i] = srcs[eid];
    attr_s[i] = make_float4(eattr[eid * 3 + 0], eattr[eid * 3 + 1], eattr[eid * 3 + 2], 0.f);
  }
}

// ---------------- bond encoder GEMM (MFMA) ----------------
template <int DE>
__global__ __launch_bounds__(256) void bond_kernel(
    const float4* __restrict__ attr_s, const float* __restrict__ be1,
    const float* __restrict__ be2, unsigned short* __restrict__ ebond, int E) {
  constexpr int KT = (DE + 31) / 32;   // 1 (DE=28) or 2 (DE=64)
  constexpr int NT = (DE + 15) / 16;   // 2 or 4
  constexpr int RB = KT * 32;          // ebond row width: 32 or 64
  constexpr int LROW = RB * 2 + 16;    // padded LDS row bytes, 16B-aligned
  __shared__ __attribute__((aligned(16))) char lds_all[4 * 16 * LROW];
  char* lds = lds_all + (threadIdx.x >> 6) * (16 * LROW);
  int lane = threadIdx.x & 63;
  int nc = lane & 15, kr = (lane >> 4) * 8, rr = (lane >> 4) * 4;
  int gw = (blockIdx.x * blockDim.x + threadIdx.x) >> 6;
  int nw = (gridDim.x * blockDim.x) >> 6;

  float b10 = 0.f, b11 = 0.f, b12 = 0.f;
  if (lane < DE) { b10 = be1[lane]; b11 = be1[DE + lane]; b12 = be1[2 * DE + lane]; }

  short8v bfrag[NT][KT];
#pragma unroll
  for (int nt = 0; nt < NT; nt++)
#pragma unroll
    for (int kt = 0; kt < KT; kt++) {
      short8v f;
#pragma unroll
      for (int j = 0; j < 8; j++) {
        int k = kt * 32 + kr + j, n = nt * 16 + nc;
        float w = (k < DE && n < DE) ? be2[k * DE + n] : 0.f;
        f[j] = (short)f2bf(w);
      }
      bfrag[nt][kt] = f;
    }

  int ntiles = (E + 15) >> 4;
  for (int tile = gw; tile < ntiles; tile += nw) {
    int j0 = __builtin_amdgcn_readfirstlane(tile) << 4;
#pragma unroll
    for (int e = 0; e < 16; e++) {
      int j = j0 + e;
      float t = 0.f;
      if (j < E) {
        float4 a = attr_s[j];  // wave-uniform -> s_load
        t = fmaxf(fmaf(a.x, b10, fmaf(a.y, b11, a.z * b12)), 0.f);
      }
      *(unsigned short*)(lds + e * LROW + lane * 2) = f2bf(t);
    }
    asm volatile("" ::: "memory");
    short8v af[KT];
#pragma unroll
    for (int kt = 0; kt < KT; kt++)
      af[kt] = *(const short8v*)(lds + (lane & 15) * LROW + (lane >> 4) * 16 + kt * 64);
    float4v acc[NT];
#pragma unroll
    for (int nt = 0; nt < NT; nt++) {
      acc[nt] = (float4v){0.f, 0.f, 0.f, 0.f};
#pragma unroll
      for (int kt = 0; kt < KT; kt++) acc[nt] = mfma16(af[kt], bfrag[nt][kt], acc[nt]);
    }
#pragma unroll
    for (int nt = 0; nt < NT; nt++)
#pragma unroll
      for (int r = 0; r < 4; r++) {
        int row = j0 + rr + r;
        if (row < E) ebond[(size_t)row * RB + nt * 16 + nc] = f2bf(acc[nt][r]);
      }
    asm volatile("" ::: "memory");
  }
}

// ---------------- edge aggregation ----------------
template <int DH, int RB>
__global__ __launch_bounds__(256) void agg_kernel(
    const float* __restrict__ h, const unsigned short* __restrict__ eb,
    const float* __restrict__ epsp, const int* __restrict__ src_sorted,
    const int* __restrict__ offs, float* __restrict__ zout, int n_nodes) {
  int wid = (blockIdx.x * blockDim.x + threadIdx.x) >> 6;
  int nw = (gridDim.x * blockDim.x) >> 6;
  int lane = threadIdx.x & 63;
  float eps1 = 1.f + epsp[0];
  const bool hl = (DH == 64) || (lane < DH);
  const bool el = (RB == 64) || (lane < RB);
  for (int v = wid; v < n_nodes; v += nw) {
    float acc = hl ? eps1 * h[(size_t)v * DH + lane] : 0.f;
    int j = offs[v], e1 = offs[v + 1];
    for (; j + 3 < e1; j += 4) {
      int s0 = src_sorted[j], s1 = src_sorted[j + 1];
      int s2 = src_sorted[j + 2], s3 = src_sorted[j + 3];
      float b0 = el ? bf2f(eb[(size_t)j * RB + lane]) : 0.f;
      float b1 = el ? bf2f(eb[(size_t)(j + 1) * RB + lane]) : 0.f;
      float b2 = el ? bf2f(eb[(size_t)(j + 2) * RB + lane]) : 0.f;
      float b3 = el ? bf2f(eb[(size_t)(j + 3) * RB + lane]) : 0.f;
      float h0 = hl ? h[(size_t)s0 * DH + lane] : 0.f;
      float h1 = hl ? h[(size_t)s1 * DH + lane] : 0.f;
      float h2 = hl ? h[(size_t)s2 * DH + lane] : 0.f;
      float h3 = hl ? h[(size_t)s3 * DH + lane] : 0.f;
      acc += fmaxf(h0 + b0, 0.f) + fmaxf(h1 + b1, 0.f) +
             fmaxf(h2 + b2, 0.f) + fmaxf(h3 + b3, 0.f);
    }
    for (; j < e1; j++) {
      int s = src_sorted[j];
      float b = el ? bf2f(eb[(size_t)j * RB + lane]) : 0.f;
      float hs = hl ? h[(size_t)s * DH + lane] : 0.f;
      acc += fmaxf(hs + b, 0.f);
    }
    if (el) zout[(size_t)v * RB + lane] = acc;
  }
}

// ---------------- node MLP + relu + BN (MFMA) ----------------
template <int DIN>
__global__ __launch_bounds__(256) void node_mfma_kernel(
    const float* __restrict__ z, const float* __restrict__ m1,
    const float* __restrict__ m2, const float* __restrict__ bng,
    const float* __restrict__ bnb, const float* __restrict__ bnm,
    const float* __restrict__ bnv, float* __restrict__ xout, int n_nodes) {
  constexpr int KT = (DIN + 31) / 32;   // 1 or 2
  constexpr int NTH = (DIN + 15) / 16;  // 2 or 4
  constexpr int ZR = KT * 32;
  constexpr int LROW = ZR * 2 + 16;
  __shared__ __attribute__((aligned(16))) char lds_all[8 * 16 * LROW];
  char* zl = lds_all + (threadIdx.x >> 6) * (16 * LROW);
  char* yl = lds_all + (4 + (threadIdx.x >> 6)) * (16 * LROW);
  int lane = threadIdx.x & 63;
  int nc = lane & 15, kr = (lane >> 4) * 8, rr = (lane >> 4) * 4;
  int gw = (blockIdx.x * blockDim.x + threadIdx.x) >> 6;
  int nw = (gridDim.x * blockDim.x) >> 6;

  short8v m1f[NTH][KT], m2f[4][KT];
#pragma unroll
  for (int nt = 0; nt < NTH; nt++)
#pragma unroll
    for (int kt = 0; kt < KT; kt++) {
      short8v f;
#pragma unroll
      for (int j = 0; j < 8; j++) {
        int k = kt * 32 + kr + j, n = nt * 16 + nc;
        float w = (k < DIN && n < DIN) ? m1[k * DIN + n] : 0.f;
        f[j] = (short)f2bf(w);
      }
      m1f[nt][kt] = f;
    }
#pragma unroll
  for (int nt = 0; nt < 4; nt++)
#pragma unroll
    for (int kt = 0; kt < KT; kt++) {
      short8v f;
#pragma unroll
      for (int j = 0; j < 8; j++) {
        int k = kt * 32 + kr + j, n = nt * 16 + nc;
        float w = (k < DIN) ? m2[k * 64 + n] : 0.f;
        f[j] = (short)f2bf(w);
      }
      m2f[nt][kt] = f;
    }
  float scv[4], shv[4];
#pragma unroll
  for (int nt = 0; nt < 4; nt++) {
    int f = nt * 16 + nc;
    float sc = bng[f] * rsqrtf(bnv[f] + 1e-5f);
    scv[nt] = sc;
    shv[nt] = bnb[f] - bnm[f] * sc;
  }

  int ntiles = (n_nodes + 15) >> 4;
  for (int tile = gw; tile < ntiles; tile += nw) {
    int v0 = __builtin_amdgcn_readfirstlane(tile) << 4;
#pragma unroll
    for (int r = 0; r < 16; r++) {
      int v = v0 + r;
      float zv = (v < n_nodes && lane < ZR) ? z[(size_t)v * ZR + lane] : 0.f;
      if (lane < ZR) *(unsigned short*)(zl + r * LROW + lane * 2) = f2bf(zv);
    }
    asm volatile("" ::: "memory");
    short8v af[KT];
#pragma unroll
    for (int kt = 0; kt < KT; kt++)
      af[kt] = *(const short8v*)(zl + (lane & 15) * LROW + (lane >> 4) * 16 + kt * 64);
    float4v acch[NTH];
#pragma unroll
    for (int nt = 0; nt < NTH; nt++) {
      acch[nt] = (float4v){0.f, 0.f, 0.f, 0.f};
#pragma unroll
      for (int kt = 0; kt < KT; kt++) acch[nt] = mfma16(af[kt], m1f[nt][kt], acch[nt]);
    }
#pragma unroll
    for (int nt = 0; nt < NTH; nt++)
#pragma unroll
      for (int r = 0; r < 4; r++)
        *(unsigned short*)(yl + (rr + r) * LROW + (nt * 16 + nc) * 2) =
            f2bf(fmaxf(acch[nt][r], 0.f));
    asm volatile("" ::: "memory");
    short8v af2[KT];
#pragma unroll
    for (int kt = 0; kt < KT; kt++)
      af2[kt] = *(const short8v*)(yl + (lane & 15) * LROW + (lane >> 4) * 16 + kt * 64);
    float4v acco[4];
#pragma unroll
    for (int nt = 0; nt < 4; nt++) {
      acco[nt] = (float4v){0.f, 0.f, 0.f, 0.f};
#pragma unroll
      for (int kt = 0; kt < KT; kt++) acco[nt] = mfma16(af2[kt], m2f[nt][kt], acco[nt]);
    }
#pragma unroll
    for (int nt = 0; nt < 4; nt++)
#pragma unroll
      for (int r = 0; r < 4; r++) {
        int v = v0 + rr + r;
        if (v < n_nodes)
          xout[(size_t)v * 64 + nt * 16 + nc] =
              fmaf(fmaxf(acco[nt][r], 0.f), scv[nt], shv[nt]);
      }
    asm volatile("" ::: "memory");
  }
}

// ---------------- graph mean-pool of concat(x1..x4) ----------------
__global__ __launch_bounds__(256) void pool_kernel(
    const float* __restrict__ x1, const float* __restrict__ x2,
    const float* __restrict__ x3, const float* __restrict__ x4,
    const int* __restrict__ goff, float* __restrict__ pooled, int G) {
  int g = blockIdx.x;
  int c = threadIdx.x;
  int sel = c >> 6, f = c & 63;
  const float* x = (sel == 0) ? x1 : (sel == 1) ? x2 : (sel == 2) ? x3 : x4;
  int s = goff[g], e = goff[g + 1];
  float acc = 0.f;
  for (int v = s; v < e; v++) acc += x[(size_t)v * 64 + f];
  float cnt = (float)(e - s);
  pooled[g * 256 + c] = acc / fmaxf(cnt, 1.0f);
}

// ---------------- FC head ----------------
__global__ __launch_bounds__(64) void head_kernel(
    const float* __restrict__ pooled,
    const float* __restrict__ w1, const float* __restrict__ b1,
    const float* __restrict__ w2, const float* __restrict__ b2,
    const float* __restrict__ w3, const float* __restrict__ b3,
    const float* __restrict__ w4, const float* __restrict__ b4,
    float* __restrict__ out, int G) {
  int g = blockIdx.x;
  int lane = threadIdx.x;
  __shared__ float sh[256];
  for (int i = lane; i < 256; i += 64) sh[i] = pooled[g * 256 + i];
  __syncthreads();
  float h1 = b1[lane];
#pragma unroll 8
  for (int i = 0; i < 256; i++) h1 = fmaf(sh[i], w1[i * 64 + lane], h1);
  h1 = fmaxf(h1, 0.f);
  __syncthreads();
  sh[lane] = h1;
  __syncthreads();
  float h2 = b2[lane];
#pragma unroll
  for (int i = 0; i < 64; i++) h2 = fmaf(sh[i], w2[i * 64 + lane], h2);
  h2 = fmaxf(h2, 0.f);
  __syncthreads();
  sh[lane] = h2;
  __syncthreads();
  float h3 = b3[lane];
#pragma unroll
  for (int i = 0; i < 64; i++) h3 = fmaf(sh[i], w3[i * 64 + lane], h3);
  h3 = fmaxf(h3, 0.f);
  float p = h3 * w4[lane];
  for (int d = 32; d > 0; d >>= 1) p += __shfl_down(p, d);
  if (lane == 0) out[g] = p + b4[0];
}

// ---------------------------------------------------------------------------

extern "C" void kernel_launch(void* const* d_in, const int* in_sizes, int n_in,
                              void* d_out, int out_size, void* d_ws, size_t ws_size,
                              hipStream_t stream) {
  const float* x      = (const float*)d_in[0];
  const float* eattr  = (const float*)d_in[1];
  const float* c1_be1 = (const float*)d_in[2];
  const float* c1_be2 = (const float*)d_in[3];
  const float* c1_m1  = (const float*)d_in[4];
  const float* c1_m2  = (const float*)d_in[5];
  const float* c1_eps = (const float*)d_in[6];
  const float* c2_be1 = (const float*)d_in[7];
  const float* c2_be2 = (const float*)d_in[8];
  const float* c2_m1  = (const float*)d_in[9];
  const float* c2_m2  = (const float*)d_in[10];
  const float* c2_eps = (const float*)d_in[11];
  const float* c3_be1 = (const float*)d_in[12];
  const float* c3_be2 = (const float*)d_in[13];
  const float* c3_m1  = (const float*)d_in[14];
  const float* c3_m2  = (const float*)d_in[15];
  const float* c3_eps = (const float*)d_in[16];
  const float* bn_g[4] = {(const float*)d_in[17], (const float*)d_in[21],
                          (const float*)d_in[25], (const float*)d_in[29]};
  const float* bn_b[4] = {(const float*)d_in[18], (const float*)d_in[22],
                          (const float*)d_in[26], (const float*)d_in[30]};
  const float* bn_m[4] = {(const float*)d_in[19], (const float*)d_in[23],
                          (const float*)d_in[27], (const float*)d_in[31]};
  const float* bn_v[4] = {(const float*)d_in[20], (const float*)d_in[24],
                          (const float*)d_in[28], (const float*)d_in[32]};
  const float* fc1_w = (const float*)d_in[33];
  const float* fc1_b = (const float*)d_in[34];
  const float* fc2_w = (const float*)d_in[35];
  const float* fc2_b = (const float*)d_in[36];
  const float* fc3_w = (const float*)d_in[37];
  const float* fc3_b = (const float*)d_in[38];
  const float* fc4_w = (const float*)d_in[39];
  const float* fc4_b = (const float*)d_in[40];
  const int* eidx  = (const int*)d_in[41];
  const int* batch = (const int*)d_in[42];

  const int N = in_sizes[0] / 28;
  const int E = in_sizes[1] / 3;
  const int G = out_size;
  const int* src = eidx;
  const int* dst = eidx + E;
  float* outf = (float*)d_out;

  char* p = (char*)d_ws;
  auto alloc = [&](size_t bytes) {
    char* r = p;
    p += (bytes + 255) & ~(size_t)255;
    return r;
  };
  const int NBLK = (N + 255) / 256;  // scan blocks (196 for N=50000)
  int* counts   = (int*)alloc((size_t)N * 4);
  int* offs     = (int*)alloc((size_t)(N + 1) * 4);
  int* cursor   = (int*)alloc((size_t)N * 4);
  int* bsum     = (int*)alloc((size_t)NBLK * 4);
  int* sorted   = (int*)alloc((size_t)E * 4);
  int* goff     = (int*)alloc((size_t)(G + 1) * 4);
  int* src_s    = (int*)alloc((size_t)E * 4);
  float4* attr_s = (float4*)alloc((size_t)E * 16);
  unsigned short* ebond = (unsigned short*)alloc((size_t)E * 64 * 2);  // reused per layer
  float* zbuf   = (float*)alloc((size_t)N * 64 * 4);
  float* x1     = (float*)alloc((size_t)N * 64 * 4);
  float* x2     = (float*)alloc((size_t)N * 64 * 4);
  float* x3     = (float*)alloc((size_t)N * 64 * 4);
  float* x4     = (float*)alloc((size_t)N * 64 * 4);
  float* pooled = (float*)alloc((size_t)G * 256 * 4);
  (void)ws_size; (void)n_in;

  hipMemsetAsync(counts, 0, (size_t)N * 4, stream);
  hist_kernel<<<1024, 256, 0, stream>>>(dst, counts, E);
  boundary_kernel<<<(G + 128) / 128, 128, 0, stream>>>(batch, goff, N, G);
  block_reduce_kernel<<<NBLK, 256, 0, stream>>>(counts, bsum, N);
  bsum_scan_kernel<<<1, 256, 0, stream>>>(bsum, NBLK);
  scan_apply_kernel<<<NBLK, 256, 0, stream>>>(counts, bsum, offs, cursor, N);
  fill_kernel<<<1024, 256, 0, stream>>>(dst, cursor, sorted, E);
  perm_kernel<<<1024, 256, 0, stream>>>(sorted, src, eattr, src_s, attr_s, E);

  dim3 blk(256);
  // layer 1
  bond_kernel<28><<<1024, blk, 0, stream>>>(attr_s, c1_be1, c1_be2, ebond, E);
  agg_kernel<28, 32><<<2048, blk, 0, stream>>>(x, ebond, c1_eps, src_s, offs, zbuf, N);
  node_mfma_kernel<28><<<1024, blk, 0, stream>>>(zbuf, c1_m1, c1_m2, bn_g[0], bn_b[0],
                                                 bn_m[0], bn_v[0], x1, N);
  // layer 2
  bond_kernel<64><<<1024, blk, 0, stream>>>(attr_s, c2_be1, c2_be2, ebond, E);
  agg_kernel<64, 64><<<2048, blk, 0, stream>>>(x1, ebond, c2_eps, src_s, offs, zbuf, N);
  node_mfma_kernel<64><<<1024, blk, 0, stream>>>(zbuf, c2_m1, c2_m2, bn_g[1], bn_b[1],
                                                 bn_m[1], bn_v[1], x2, N);
  // layer 3
  bond_kernel<64><<<1024, blk, 0, stream>>>(attr_s, c3_be1, c3_be2, ebond, E);
  agg_kernel<64, 64><<<2048, blk, 0, stream>>>(x2, ebond, c3_eps, src_s, offs, zbuf, N);
  node_mfma_kernel<64><<<1024, blk, 0, stream>>>(zbuf, c3_m1, c3_m2, bn_g[2], bn_b[2],
                                                 bn_m[2], bn_v[2], x3, N);
  // layer 4 (conv3 weights reused -> ebond already holds c3 bond encodings)
  agg_kernel<64, 64><<<2048, blk, 0, stream>>>(x3, ebond, c3_eps, src_s, offs, zbuf, N);
  node_mfma_kernel<64><<<1024, blk, 0, stream>>>(zbuf, c3_m1, c3_m2, bn_g[3], bn_b[3],
                                                 bn_m[3], bn_v[3], x4, N);

  pool_kernel<<<G, blk, 0, stream>>>(x1, x2, x3, x4, goff, pooled, G);
  head_kernel<<<G, 64, 0, stream>>>(pooled, fc1_w, fc1_b, fc2_w, fc2_b, fc3_w,
                                    fc3_b, fc4_w, fc4_b, outf, G);
}